// Round 8
// baseline (116.608 us; speedup 1.0000x reference)
//
#include <hip/hip_runtime.h>
#include <math.h>

#define TPB 256

typedef _Float16 f16x8 __attribute__((ext_vector_type(8)));
typedef float    f32x4 __attribute__((ext_vector_type(4)));

#define MFMA16(A, B, C) __builtin_amdgcn_mfma_f32_16x16x32_f16((A), (B), (C), 0, 0, 0)

// out = 0.25 * K^T * silu(K x K^T) * K per 64x64 image (math + chain verified R6/R7).
// R8 vs R7 (R7 regressed: direct global dword scatter -> 64B partial-line writes,
// WRITE_SIZE 32.8->53.2 MB, FETCH 16.4->31.5 MB):
//  (a) S4 -> buf4 (row-major f32 [64][68] = out itself) via SCALAR b32 stores:
//      bank = (16*lq + ln) mod 32 -> 2 lanes/bank (free, m136). Writeout = aligned
//      float4 row reads (uniform banks) + full-256B-row coalesced global stores.
//  (b) cross-image prefetch: next image's 4 float4 loads issued at stage-in end,
//      consumed one image-body later (~4000 cyc) -> HBM latency hidden.
//  (c) buf4 at bufA+8KB, disjoint from buf0 [0,8KB) -> writeout reads & next
//      stage-in writes unordered -> 5 barriers/image (was 6).
// Chain (verified R6/R7; zero explicit transposes):
//   buf0 = x;  S1: D1 = x*K^T -> buf1 = D1^T;  S2: D2 = K*buf1^T = u, silu -> buf2 = S^T;
//   S3: D3 = buf2*K = S^T K -> buf3 = D3^T;  S4: D4 = buf3*K = K^T S K = 4*out -> buf4.
// XOR 16B-block swizzle (verified R7): uniform banks for all b128 frag reads/b64 stores.

__device__ __forceinline__ int sw64(int r, int c) {   // u16 index, 64-col buffer
  return (r << 6) + (c & 7) + ((((c >> 3) ^ r) & 7) << 3);
}
__device__ __forceinline__ int sw128(int r, int c) {  // u16 index, 128-col buffer
  return (r << 7) + (c & 7) + ((((c >> 3) ^ (r & 7))) << 3);
}

__device__ __forceinline__ void store4h(_Float16* p, float a0, float a1, float a2, float a3) {
  float2 q;
  q.x = __builtin_bit_cast(float, __builtin_amdgcn_cvt_pkrtz(a0, a1));  // low half = a0
  q.y = __builtin_bit_cast(float, __builtin_amdgcn_cvt_pkrtz(a2, a3));
  *(float2*)p = q;  // ds_write_b64
}

__global__ __launch_bounds__(TPB, 3) void warped_mfma(const float* __restrict__ xin,
                                                      float* __restrict__ outp, int nimg) {
  constexpr int SZ = 68;  // f32 stride of buf4 (16B-multiple rows; scalar writes 2-way free)

  __shared__ __attribute__((aligned(16))) _Float16 bufA[128 * 128];  // 32768 B
  __shared__ __attribute__((aligned(16))) _Float16 bufB[128 * 64];   // 16384 B
  __shared__ float k1d[128];

  _Float16* const buf0 = bufA;                        // [64][64]   x, stage-in -> S1
  _Float16* const buf2 = bufA;                        // [128][128] S^T, S2 -> S3
  float*    const buf4 = (float*)(bufA + 4096);       // [64][68] f32 = out, S4 -> writeout
  _Float16* const buf1 = bufB;                        // [128][64]  D1^T, S1 -> S2
  _Float16* const buf3 = bufB;                        // [64][128]  D3^T, S3 -> S4

  const int tid = threadIdx.x;
  const int lane = tid & 63;
  const int w  = tid >> 6;  // wave 0..3
  const int wk = w >> 1;    // K-tile half (shared-frag axis)
  const int wd = w & 1;     // data-tile half
  const int lq = lane >> 4; // quad 0..3 (k dim of frags)
  const int ln = lane & 15; // m/n dim of frags

  // ---- 1D half-band kernel (verified R1): k(d) = (1/64)[1 + 2*sum cos(pi f d/64) + cos(pi d/2)]
  if (tid < 128) {
    const int d = tid;
    float s = 1.0f + ((d & 1) ? 0.0f : ((d & 2) ? -1.0f : 1.0f));
    for (int f = 1; f <= 31; ++f) {
      int r = (f * d) & 127;
      s += 2.0f * __cosf((float)r * 0.04908738521234052f /* pi/64 */);
    }
    k1d[d] = s * (1.0f / 64.0f);
  }
  __syncthreads();

  // ---- K fragments in registers (once per WG; verified R6/R7)
  f16x8 AK[4][2];  // K rows a=(wk*4+t)*16+ln; S1 B-operand & S2 A-operand
#pragma unroll
  for (int t = 0; t < 4; ++t)
#pragma unroll
    for (int ks = 0; ks < 2; ++ks) {
      const int a = (wk * 4 + t) * 16 + ln;
      f16x8 f;
#pragma unroll
      for (int j = 0; j < 8; ++j) {
        int k = ks * 32 + lq * 8 + j;
        f[j] = (_Float16)k1d[(a - 2 * k) & 127];
      }
      AK[t][ks] = f;
    }
  f16x8 BT[2][4];  // B[k][c] = K[k][c], c=(wk*2+t)*16+ln; S3 & S4 B-operand
#pragma unroll
  for (int t = 0; t < 2; ++t)
#pragma unroll
    for (int ks = 0; ks < 4; ++ks) {
      const int c = (wk * 2 + t) * 16 + ln;
      f16x8 f;
#pragma unroll
      for (int j = 0; j < 8; ++j) {
        int k = ks * 32 + lq * 8 + j;
        f[j] = (_Float16)k1d[(k - 2 * c) & 127];
      }
      BT[t][ks] = f;
    }

  const f32x4 vzero = {0.0f, 0.0f, 0.0f, 0.0f};

  // ---- prefetch image 0
  float4 pf[4];
  {
    const float4* xp = (const float4*)(xin + (size_t)blockIdx.x * 4096);
#pragma unroll
    for (int rep = 0; rep < 4; ++rep) pf[rep] = xp[rep * 256 + tid];
  }

  for (int img = blockIdx.x; img < nimg; img += gridDim.x) {
    float* __restrict__ out = outp + (size_t)img * 4096;

    // ---- stage-in: buf0[i][j] = x[i][j] f16 from prefetched regs; then issue next prefetch
#pragma unroll
    for (int rep = 0; rep < 4; ++rep) {
      int idx = rep * 256 + tid;
      int i = idx >> 4, j0 = (idx & 15) << 2;
      store4h(buf0 + sw64(i, j0), pf[rep].x, pf[rep].y, pf[rep].z, pf[rep].w);
    }
    {
      int img2 = img + gridDim.x;
      if (img2 < nimg) {
        const float4* xp = (const float4*)(xin + (size_t)img2 * 4096);
#pragma unroll
        for (int rep = 0; rep < 4; ++rep) pf[rep] = xp[rep * 256 + tid];
      }
    }
    __syncthreads();  // B0

    // ---- S1: D1 = x*K^T (64x128). m-tiles wd*2+{0,1}, n-tiles wk*4+{0..3}, ks 0..1.
    {
      f32x4 acc[2][4];
#pragma unroll
      for (int mtl = 0; mtl < 2; ++mtl)
#pragma unroll
        for (int ntl = 0; ntl < 4; ++ntl) acc[mtl][ntl] = vzero;
#pragma unroll
      for (int ks = 0; ks < 2; ++ks) {
        f16x8 Ad[2];
#pragma unroll
        for (int mtl = 0; mtl < 2; ++mtl)
          Ad[mtl] = *(const f16x8*)(buf0 + sw64((wd * 2 + mtl) * 16 + ln, ks * 32 + lq * 8));
#pragma unroll
        for (int mtl = 0; mtl < 2; ++mtl)
#pragma unroll
          for (int ntl = 0; ntl < 4; ++ntl)
            acc[mtl][ntl] = MFMA16(Ad[mtl], AK[ntl][ks], acc[mtl][ntl]);
      }
#pragma unroll
      for (int mtl = 0; mtl < 2; ++mtl)
#pragma unroll
        for (int ntl = 0; ntl < 4; ++ntl) {
          int n0 = (wk * 4 + ntl) * 16, m0 = (wd * 2 + mtl) * 16;
          f32x4 a = acc[mtl][ntl];
          store4h(buf1 + sw64(n0 + ln, m0 + lq * 4), a[0], a[1], a[2], a[3]);
        }
    }
    __syncthreads();  // B1

    // ---- S2: D2 = K*buf1^T = u (128x128), silu -> buf2 (over buf0, dead since B1).
#pragma unroll
    for (int nh = 0; nh < 2; ++nh) {
      f32x4 acc[4][2];
#pragma unroll
      for (int mtl = 0; mtl < 4; ++mtl)
#pragma unroll
        for (int ntl = 0; ntl < 2; ++ntl) acc[mtl][ntl] = vzero;
#pragma unroll
      for (int ks = 0; ks < 2; ++ks) {
        f16x8 Bd[2];
#pragma unroll
        for (int ntl = 0; ntl < 2; ++ntl)
          Bd[ntl] = *(const f16x8*)(buf1 +
                                    sw64((wd * 4 + nh * 2 + ntl) * 16 + ln, ks * 32 + lq * 8));
#pragma unroll
        for (int mtl = 0; mtl < 4; ++mtl)
#pragma unroll
          for (int ntl = 0; ntl < 2; ++ntl)
            acc[mtl][ntl] = MFMA16(AK[mtl][ks], Bd[ntl], acc[mtl][ntl]);
      }
#pragma unroll
      for (int mtl = 0; mtl < 4; ++mtl)
#pragma unroll
        for (int ntl = 0; ntl < 2; ++ntl) {
          int n0 = (wd * 4 + nh * 2 + ntl) * 16, m0 = (wk * 4 + mtl) * 16;
          float s[4];
#pragma unroll
          for (int r = 0; r < 4; ++r) {
            float u = acc[mtl][ntl][r];
            s[r] = u * __builtin_amdgcn_rcpf(1.0f + __expf(-u));  // silu
          }
          store4h(buf2 + sw128(n0 + ln, m0 + lq * 4), s[0], s[1], s[2], s[3]);
        }
    }
    __syncthreads();  // B2

    // ---- S3: D3 = buf2*K = S^T K (128x64) -> buf3 (over buf1, dead since B2).
    {
      f32x4 acc[4][2];
#pragma unroll
      for (int mtl = 0; mtl < 4; ++mtl)
#pragma unroll
        for (int ntl = 0; ntl < 2; ++ntl) acc[mtl][ntl] = vzero;
#pragma unroll
      for (int ks = 0; ks < 4; ++ks) {
        f16x8 Ad[4];
#pragma unroll
        for (int mtl = 0; mtl < 4; ++mtl)
          Ad[mtl] = *(const f16x8*)(buf2 + sw128((wd * 4 + mtl) * 16 + ln, ks * 32 + lq * 8));
#pragma unroll
        for (int mtl = 0; mtl < 4; ++mtl)
#pragma unroll
          for (int ntl = 0; ntl < 2; ++ntl)
            acc[mtl][ntl] = MFMA16(Ad[mtl], BT[ntl][ks], acc[mtl][ntl]);
      }
#pragma unroll
      for (int mtl = 0; mtl < 4; ++mtl)
#pragma unroll
        for (int ntl = 0; ntl < 2; ++ntl) {
          int n0 = (wk * 2 + ntl) * 16, m0 = (wd * 4 + mtl) * 16;
          f32x4 a = acc[mtl][ntl];
          store4h(buf3 + sw128(n0 + ln, m0 + lq * 4), a[0], a[1], a[2], a[3]);
        }
    }
    __syncthreads();  // B3 (orders buf3 writes->S4 reads AND buf2 reads->buf4 writes)

    // ---- S4: D4 = buf3*K = 4*out (64x64) -> buf4 scalar b32 stores (2 lanes/bank).
    {
      f32x4 acc[2][2];
#pragma unroll
      for (int mtl = 0; mtl < 2; ++mtl)
#pragma unroll
        for (int ntl = 0; ntl < 2; ++ntl) acc[mtl][ntl] = vzero;
#pragma unroll
      for (int ks = 0; ks < 4; ++ks) {
        f16x8 Ad[2];
#pragma unroll
        for (int mtl = 0; mtl < 2; ++mtl)
          Ad[mtl] = *(const f16x8*)(buf3 + sw128((wd * 2 + mtl) * 16 + ln, ks * 32 + lq * 8));
#pragma unroll
        for (int mtl = 0; mtl < 2; ++mtl)
#pragma unroll
          for (int ntl = 0; ntl < 2; ++ntl)
            acc[mtl][ntl] = MFMA16(Ad[mtl], BT[ntl][ks], acc[mtl][ntl]);
      }
#pragma unroll
      for (int mtl = 0; mtl < 2; ++mtl)
#pragma unroll
        for (int ntl = 0; ntl < 2; ++ntl) {
          int n0 = (wk * 2 + ntl) * 16, m0 = (wd * 2 + mtl) * 16;
#pragma unroll
          for (int r = 0; r < 4; ++r)
            buf4[(m0 + lq * 4 + r) * SZ + n0 + ln] = 0.25f * acc[mtl][ntl][r];
        }
    }
    __syncthreads();  // B4

    // ---- writeout: out rows straight from buf4 (aligned float4, full 256B rows/instr)
#pragma unroll
    for (int rep = 0; rep < 4; ++rep) {
      int a = (tid >> 4) + rep * 16;
      int b0 = (tid & 15) << 2;
      float4 o = *(const float4*)(buf4 + a * SZ + b0);
      ((float4*)out)[(a * 64 + b0) >> 2] = o;
    }
    // no trailing barrier: next stage-in writes buf0 [0,8KB), disjoint from buf4 [8KB,25.4KB)
  }
}

extern "C" void kernel_launch(void* const* d_in, const int* in_sizes, int n_in,
                              void* d_out, int out_size, void* d_ws, size_t ws_size,
                              hipStream_t stream) {
  const float* x = (const float*)d_in[0];
  float* out = (float*)d_out;
  const int nimg = in_sizes[0] / 4096;  // B*C images of 64x64
  const int grid = (nimg + 1) / 2;      // 2 images per WG
  warped_mfma<<<dim3(grid), dim3(TPB), 0, stream>>>(x, out, nimg);
}

// Round 9
// 93.881 us; speedup vs baseline: 1.2421x; 1.2421x over previous
//
#include <hip/hip_runtime.h>
#include <math.h>

#define TPB 256

typedef _Float16 f16x8 __attribute__((ext_vector_type(8)));
typedef float    f32x4 __attribute__((ext_vector_type(4)));

#define MFMA16(A, B, C) __builtin_amdgcn_mfma_f32_16x16x32_f16((A), (B), (C), 0, 0, 0)

// out = 0.25 * K^T * silu(K x K^T) * K per 64x64 image (math + chain verified R6, absmax 1.56e-2).
// R9 = R6's additive-stride body (XOR swizzle of R7/R8 reverted: it halved conflicts but its
// inseparable address math cost ~5-7us of VALU — R6 72 VGPR vs R8 84) with:
//  (a) cross-image register prefetch (issue next image's 4 float4 loads during stage-in,
//      consume one image-body later -> HBM latency hidden);
//  (b) S4 -> buf4 row-major f32 [64][68] via scalar b32 (banks 16lq+ln -> 2/bank, free);
//      writeout = aligned float4 row reads (uniform 8/bank) + full-256B coalesced stores
//      (replaces R6's 8-way-conflicted transposed writeout reads);
//  (c) buf4 at bufA+9216B, disjoint from buf0 [0,9216) -> no trailing barrier;
//      redundant mid-stage barriers of R6 dropped -> 5 barriers/image (R6 had ~8).
// Bank audit (additive strides, dword-stride ≡ 4 mod 32): b128 frag reads uniform 8/bank
// (free); b64 D^T stores even-banks-only (2x, ~3% — accepted).
// Chain (verified R6; zero explicit transposes; B-read gives the transpose, C/D col-store
// gives D^T for free):
//   buf0 = x;  S1: D1 = x*K^T -> buf1 = D1^T;  S2: D2 = K*buf1^T = u, silu -> buf2 = S^T;
//   S3: D3 = buf2*K = S^T K -> buf3 = D3^T;  S4: D4 = buf3*K = K^T S K = 4*out -> buf4.

__device__ __forceinline__ void store4h(_Float16* p, float a0, float a1, float a2, float a3) {
  float2 q;
  q.x = __builtin_bit_cast(float, __builtin_amdgcn_cvt_pkrtz(a0, a1));  // low half = a0
  q.y = __builtin_bit_cast(float, __builtin_amdgcn_cvt_pkrtz(a2, a3));
  *(float2*)p = q;  // ds_write_b64
}

__global__ __launch_bounds__(TPB, 3) void warped_mfma(const float* __restrict__ xin,
                                                      float* __restrict__ outp, int nimg) {
  constexpr int SA = 72;   // u16 stride: buf0 [64][72], buf1 [128][72]  (rows 16B-aligned)
  constexpr int SB = 136;  // u16 stride: buf2 [128][136], buf3 [64][136]
  constexpr int SZ = 68;   // f32 stride: buf4 [64][68]

  __shared__ __attribute__((aligned(16))) _Float16 bufA[128 * SB];  // 34816 B
  __shared__ __attribute__((aligned(16))) _Float16 bufB[128 * SA];  // 18432 B
  __shared__ float k1d[128];

  _Float16* const buf0 = bufA;                              // [64][72]   x, stage-in -> S1
  _Float16* const buf2 = bufA;                              // [128][136] S^T, S2 -> S3
  float*    const buf4 = (float*)((char*)bufA + 9216);      // [64][68] f32 = out, S4 -> wo
  _Float16* const buf1 = bufB;                              // [128][72]  D1^T, S1 -> S2
  _Float16* const buf3 = bufB;                              // [64][136]  D3^T, S3 -> S4

  const int tid = threadIdx.x;
  const int lane = tid & 63;
  const int w  = tid >> 6;  // wave 0..3
  const int wk = w >> 1;    // K-tile half (shared-frag axis)
  const int wd = w & 1;     // data-tile half
  const int lq = lane >> 4; // quad 0..3 (k dim of frags)
  const int ln = lane & 15; // m/n dim of frags

  // ---- 1D half-band kernel (verified R1): k(d) = (1/64)[1 + 2*sum cos(pi f d/64) + cos(pi d/2)]
  if (tid < 128) {
    const int d = tid;
    float s = 1.0f + ((d & 1) ? 0.0f : ((d & 2) ? -1.0f : 1.0f));
    for (int f = 1; f <= 31; ++f) {
      int r = (f * d) & 127;
      s += 2.0f * __cosf((float)r * 0.04908738521234052f /* pi/64 */);
    }
    k1d[d] = s * (1.0f / 64.0f);
  }
  __syncthreads();

  // ---- K fragments in registers (once per WG; verified R6)
  f16x8 AK[4][2];  // K rows a=(wk*4+t)*16+ln; S1 B-operand & S2 A-operand
#pragma unroll
  for (int t = 0; t < 4; ++t)
#pragma unroll
    for (int ks = 0; ks < 2; ++ks) {
      const int a = (wk * 4 + t) * 16 + ln;
      f16x8 f;
#pragma unroll
      for (int j = 0; j < 8; ++j) {
        int k = ks * 32 + lq * 8 + j;
        f[j] = (_Float16)k1d[(a - 2 * k) & 127];
      }
      AK[t][ks] = f;
    }
  f16x8 BT[2][4];  // B[k][c] = K[k][c], c=(wk*2+t)*16+ln; S3 & S4 B-operand
#pragma unroll
  for (int t = 0; t < 2; ++t)
#pragma unroll
    for (int ks = 0; ks < 4; ++ks) {
      const int c = (wk * 2 + t) * 16 + ln;
      f16x8 f;
#pragma unroll
      for (int j = 0; j < 8; ++j) {
        int k = ks * 32 + lq * 8 + j;
        f[j] = (_Float16)k1d[(k - 2 * c) & 127];
      }
      BT[t][ks] = f;
    }

  const f32x4 vzero = {0.0f, 0.0f, 0.0f, 0.0f};

  // ---- prefetch image 0
  float4 pf[4];
  {
    const float4* xp = (const float4*)(xin + (size_t)blockIdx.x * 4096);
#pragma unroll
    for (int rep = 0; rep < 4; ++rep) pf[rep] = xp[rep * 256 + tid];
  }

  for (int img = blockIdx.x; img < nimg; img += gridDim.x) {
    float* __restrict__ out = outp + (size_t)img * 4096;

    // ---- stage-in: buf0[i][j] = x[i][j] f16 from prefetched regs; issue next prefetch
#pragma unroll
    for (int rep = 0; rep < 4; ++rep) {
      int idx = rep * 256 + tid;
      int i = idx >> 4, j0 = (idx & 15) << 2;
      store4h(buf0 + i * SA + j0, pf[rep].x, pf[rep].y, pf[rep].z, pf[rep].w);
    }
    {
      int img2 = img + gridDim.x;
      if (img2 < nimg) {
        const float4* xp = (const float4*)(xin + (size_t)img2 * 4096);
#pragma unroll
        for (int rep = 0; rep < 4; ++rep) pf[rep] = xp[rep * 256 + tid];
      }
    }
    __syncthreads();  // B0

    // ---- S1: D1 = x*K^T (64x128). m-tiles wd*2+{0,1}, n-tiles wk*4+{0..3}, ks 0..1.
    {
      f32x4 acc[2][4];
#pragma unroll
      for (int mtl = 0; mtl < 2; ++mtl)
#pragma unroll
        for (int ntl = 0; ntl < 4; ++ntl) acc[mtl][ntl] = vzero;
#pragma unroll
      for (int ks = 0; ks < 2; ++ks) {
        f16x8 Ad[2];
#pragma unroll
        for (int mtl = 0; mtl < 2; ++mtl)
          Ad[mtl] = *(const f16x8*)(buf0 + ((wd * 2 + mtl) * 16 + ln) * SA + ks * 32 + lq * 8);
#pragma unroll
        for (int mtl = 0; mtl < 2; ++mtl)
#pragma unroll
          for (int ntl = 0; ntl < 4; ++ntl)
            acc[mtl][ntl] = MFMA16(Ad[mtl], AK[ntl][ks], acc[mtl][ntl]);
      }
      // store D1^T: buf1[n][m] (4 col-consecutive accs -> one b64)
#pragma unroll
      for (int mtl = 0; mtl < 2; ++mtl)
#pragma unroll
        for (int ntl = 0; ntl < 4; ++ntl) {
          int n0 = (wk * 4 + ntl) * 16, m0 = (wd * 2 + mtl) * 16;
          f32x4 a = acc[mtl][ntl];
          store4h(buf1 + (n0 + ln) * SA + m0 + lq * 4, a[0], a[1], a[2], a[3]);
        }
    }
    __syncthreads();  // B1 (orders buf0 reads -> S2's bufA writes; buf1 writes -> S2 reads)

    // ---- S2: D2 = K*buf1^T = u (128x128), silu -> buf2 (bufA; buf0 dead).
#pragma unroll
    for (int nh = 0; nh < 2; ++nh) {
      f32x4 acc[4][2];
#pragma unroll
      for (int mtl = 0; mtl < 4; ++mtl)
#pragma unroll
        for (int ntl = 0; ntl < 2; ++ntl) acc[mtl][ntl] = vzero;
#pragma unroll
      for (int ks = 0; ks < 2; ++ks) {
        f16x8 Bd[2];
#pragma unroll
        for (int ntl = 0; ntl < 2; ++ntl)
          Bd[ntl] = *(const f16x8*)(buf1 + ((wd * 4 + nh * 2 + ntl) * 16 + ln) * SA +
                                    ks * 32 + lq * 8);
#pragma unroll
        for (int mtl = 0; mtl < 4; ++mtl)
#pragma unroll
          for (int ntl = 0; ntl < 2; ++ntl)
            acc[mtl][ntl] = MFMA16(AK[mtl][ks], Bd[ntl], acc[mtl][ntl]);
      }
#pragma unroll
      for (int mtl = 0; mtl < 4; ++mtl)
#pragma unroll
        for (int ntl = 0; ntl < 2; ++ntl) {
          int n0 = (wd * 4 + nh * 2 + ntl) * 16, m0 = (wk * 4 + mtl) * 16;
          float s[4];
#pragma unroll
          for (int r = 0; r < 4; ++r) {
            float u = acc[mtl][ntl][r];
            s[r] = u * __builtin_amdgcn_rcpf(1.0f + __expf(-u));  // silu
          }
          store4h(buf2 + (n0 + ln) * SB + m0 + lq * 4, s[0], s[1], s[2], s[3]);
        }
    }
    __syncthreads();  // B2 (buf1 reads -> S3's buf3 writes; buf2 writes -> S3 reads)

    // ---- S3: D3 = buf2*K = S^T K (128x64) -> buf3 (bufB; buf1 dead).
    {
      f32x4 acc[4][2];
#pragma unroll
      for (int mtl = 0; mtl < 4; ++mtl)
#pragma unroll
        for (int ntl = 0; ntl < 2; ++ntl) acc[mtl][ntl] = vzero;
#pragma unroll
      for (int ks = 0; ks < 4; ++ks) {
        f16x8 Ad[4];
#pragma unroll
        for (int mtl = 0; mtl < 4; ++mtl)
          Ad[mtl] = *(const f16x8*)(buf2 + ((wd * 4 + mtl) * 16 + ln) * SB + ks * 32 + lq * 8);
#pragma unroll
        for (int mtl = 0; mtl < 4; ++mtl)
#pragma unroll
          for (int ntl = 0; ntl < 2; ++ntl)
            acc[mtl][ntl] = MFMA16(Ad[mtl], BT[ntl][ks], acc[mtl][ntl]);
      }
#pragma unroll
      for (int mtl = 0; mtl < 4; ++mtl)
#pragma unroll
        for (int ntl = 0; ntl < 2; ++ntl) {
          int n0 = (wk * 2 + ntl) * 16, m0 = (wd * 4 + mtl) * 16;
          f32x4 a = acc[mtl][ntl];
          store4h(buf3 + (n0 + ln) * SB + m0 + lq * 4, a[0], a[1], a[2], a[3]);
        }
    }
    __syncthreads();  // B3 (buf3 writes -> S4 reads; buf2 reads -> S4's buf4 writes)

    // ---- S4: D4 = buf3*K = 4*out (64x64) -> buf4 scalar b32 (banks 16lq+ln: 2/bank free).
    {
      f32x4 acc[2][2];
#pragma unroll
      for (int mtl = 0; mtl < 2; ++mtl)
#pragma unroll
        for (int ntl = 0; ntl < 2; ++ntl) acc[mtl][ntl] = vzero;
#pragma unroll
      for (int ks = 0; ks < 4; ++ks) {
        f16x8 Ad[2];
#pragma unroll
        for (int mtl = 0; mtl < 2; ++mtl)
          Ad[mtl] = *(const f16x8*)(buf3 + ((wd * 2 + mtl) * 16 + ln) * SB + ks * 32 + lq * 8);
#pragma unroll
        for (int mtl = 0; mtl < 2; ++mtl)
#pragma unroll
          for (int ntl = 0; ntl < 2; ++ntl)
            acc[mtl][ntl] = MFMA16(Ad[mtl], BT[ntl][ks], acc[mtl][ntl]);
      }
#pragma unroll
      for (int mtl = 0; mtl < 2; ++mtl)
#pragma unroll
        for (int ntl = 0; ntl < 2; ++ntl) {
          int n0 = (wk * 2 + ntl) * 16, m0 = (wd * 2 + mtl) * 16;
#pragma unroll
          for (int r = 0; r < 4; ++r)
            buf4[(m0 + lq * 4 + r) * SZ + n0 + ln] = 0.25f * acc[mtl][ntl][r];
        }
    }
    __syncthreads();  // B4

    // ---- writeout: full rows from buf4 (aligned float4, uniform banks) -> 1KB/wave stores
#pragma unroll
    for (int rep = 0; rep < 4; ++rep) {
      int a = (tid >> 4) + rep * 16;
      int b0 = (tid & 15) << 2;
      float4 o = *(const float4*)(buf4 + a * SZ + b0);
      ((float4*)out)[(a * 64 + b0) >> 2] = o;
    }
    // no trailing barrier: next stage-in writes buf0 [0,9216)B, disjoint from buf4
    // [9216,26624)B; next S2's bufA-wide writes are behind B0+B1.
  }
}

extern "C" void kernel_launch(void* const* d_in, const int* in_sizes, int n_in,
                              void* d_out, int out_size, void* d_ws, size_t ws_size,
                              hipStream_t stream) {
  const float* x = (const float*)d_in[0];
  float* out = (float*)d_out;
  const int nimg = in_sizes[0] / 4096;  // B*C images of 64x64
  const int grid = (nimg + 1) / 2;      // 2 images per WG
  warped_mfma<<<dim3(grid), dim3(TPB), 0, stream>>>(x, out, nimg);
}